// Round 5
// baseline (97.582 us; speedup 1.0000x reference)
//
#include <hip/hip_runtime.h>
#include <hip/hip_bf16.h>

#define B_   32
#define C_   16
#define H_   256
#define W_   256
#define HW_  65536      // H_*W_
#define HID_ 128
#define T_   4          // rows per block
#define NBLK_ (B_*H_/T_)   // 2048 blocks, 64 per image

typedef __attribute__((ext_vector_type(8))) short bf16x8;
typedef __attribute__((ext_vector_type(4))) float f32x4;

__device__ __forceinline__ short f2bf(float f) {
    __hip_bfloat16 h = __float2bfloat16(f);
    return __builtin_bit_cast(short, h);
}

// hardware packed f32->bf16 RNE (no builtin on gfx950)
__device__ __forceinline__ int cvt_pk_bf16(float lo, float hi) {
    int r;
    asm("v_cvt_pk_bf16_f32 %0, %1, %2" : "=v"(r) : "v"(lo), "v"(hi));
    return r;
}

// ---------------- prep: fold w1 into per-o {A,B,C,b1} ------------------------
__global__ __launch_bounds__(128) void nca_prep(
    const float* __restrict__ w1, const float* __restrict__ b1,
    float4* __restrict__ coef4)
{
    int o = threadIdx.x;   // 0..127
    float A = 0.f, Bc = 0.f, Cc = 0.f;
    #pragma unroll
    for (int k = 0;  k < 16; ++k) A  += w1[o*48 + k];
    #pragma unroll
    for (int k = 16; k < 32; ++k) Bc += w1[o*48 + k];
    #pragma unroll
    for (int k = 32; k < 48; ++k) Cc += w1[o*48 + k];
    coef4[o] = make_float4(A, Bc, Cc, b1[o]);
}

// ---------------- fused: channel-sum + sobel + MLP + update + alpha ----------
// Block = 256 threads = one full row; col = tid. T_=4 rows/block, 2048 blocks.
// Row sums in LDS srow[T_+2][W]; x read ONCE per row (pipelined 1 row ahead).
// Layer-2 A-frags live in block-shared LDS (w2lds) to keep VGPR <= 64.
// Epilogue: direct scatter stores from MFMA acc layout (r3-validated).
__global__ __launch_bounds__(256, 4) void nca_fused(
    const float* __restrict__ x, const int* __restrict__ mask,
    const float4* __restrict__ coef4, const float* __restrict__ w2,
    const float* __restrict__ b2,
    float* __restrict__ out, unsigned char* __restrict__ alpha)
{
    __shared__ float srow[T_+2][W_];   // 6 KB
    __shared__ short hlds[4*2048];     // 16 KB: per-wave 4KB h-tile
    __shared__ short w2lds[4*64*8];    // 4 KB: [kb][lane] -> A-frag bf16x8

    const int tid  = threadIdx.x;
    const int lane = tid & 63;
    const int widx = tid >> 6;
    const int col  = tid;              // owner column 0..255
    const int q = lane & 15;           // MFMA col lane
    const int g = lane >> 4;           // MFMA k-group

    const int blk = blockIdx.x;
    const int b   = blk >> 6;          // 64 blocks per image
    const int r0  = (blk & 63) * T_;

    const float* xb = x    + (size_t)b * C_ * HW_;
    const int*   mb = mask + (size_t)b * HW_;
    float*       ob = (float*)out + (size_t)b * C_ * HW_;
    unsigned char* ab = alpha + (size_t)b * HW_;

    // ---- stage layer-2 A-frags to LDS: w2lds[kb*64+lane] = bf16x8 -----------
    {
        const int kb = tid >> 6, l = tid & 63;
        const int qq = l & 15, gg = l >> 4;
        const float* wp = w2 + qq*HID_ + kb*32 + gg*8;
        bf16x8 a;
        #pragma unroll
        for (int j = 0; j < 8; ++j) a[j] = f2bf(wp[j]);
        *(bf16x8*)(w2lds + tid*8) = a;   // lane-linear -> conflict-free reads
    }

    f32x4 bias;
    #pragma unroll
    for (int r = 0; r < 4; ++r) bias[r] = b2[g*4 + r];

    const int wswz = (lane ^ (lane >> 2)) & 3;   // h-tile write swizzle
    const int rsw  = (q ^ (q >> 2)) & 3;         // h-tile read swizzle
    short* hw = hlds + widx*2048;                // 4KB per wave

    // ---- prologue: sums for rows r0-1, r0; pipeline loads for r0+1 ----------
    float xnext[C_];
    {
        float s0 = 0.f;
        if (r0 > 0) {
            #pragma unroll
            for (int c = 0; c < C_; ++c)
                s0 += xb[c*HW_ + (r0-1)*W_ + col];
        }
        float s1 = 0.f;
        #pragma unroll
        for (int c = 0; c < C_; ++c)
            s1 += xb[c*HW_ + r0*W_ + col];
        #pragma unroll
        for (int c = 0; c < C_; ++c)
            xnext[c] = xb[c*HW_ + (r0+1)*W_ + col];
        srow[0][col] = s0;
        srow[1][col] = s1;
    }

    for (int r = 0; r < T_; ++r) {
        const int row = r0 + r;

        // finish pipelined sum for row+1 -> slot r+2
        {
            float s = 0.f;
            #pragma unroll
            for (int c = 0; c < C_; ++c) s += xnext[c];
            srow[r+2][col] = s;
        }
        __syncthreads();   // also covers w2lds/srow[0..1] staging at r==0

        // issue next row's sum loads (row r0+r+2); zero below image bottom
        if (r < T_-1) {
            const int nr = r0 + r + 2;
            if (nr < H_) {
                #pragma unroll
                for (int c = 0; c < C_; ++c)
                    xnext[c] = xb[c*HW_ + nr*W_ + col];
            } else {
                #pragma unroll
                for (int c = 0; c < C_; ++c) xnext[c] = 0.f;
            }
        }

        // prefetch mask for this wave's 64-px strip (consumed in epilogue)
        const int pstrip = row*W_ + (widx << 6);
        float mv[4];
        #pragma unroll
        for (int t = 0; t < 4; ++t)
            mv[t] = (float)mb[pstrip + t*16 + q];

        // ---- sobel on channel-sums from LDS ----
        const bool jm = col > 0, jp = col < W_-1;
        const float* sA = srow[r];
        const float* sB = srow[r+1];
        const float* sC = srow[r+2];
        float n00 = jm ? sA[col-1] : 0.f, n01 = sA[col], n02 = jp ? sA[col+1] : 0.f;
        float n10 = jm ? sB[col-1] : 0.f, n11 = sB[col], n12 = jp ? sB[col+1] : 0.f;
        float n20 = jm ? sC[col-1] : 0.f, n21 = sC[col], n22 = jp ? sC[col+1] : 0.f;
        float px = (n02 - n00) + 2.f*(n12 - n10) + (n22 - n20);
        float py = (n20 - n00) + 2.f*(n21 - n01) + (n22 - n02);
        float sc = n11;

        // ---- layer 1 + MFMA layer 2 (validated structure) ----
        f32x4 acc[4];
        #pragma unroll
        for (int t = 0; t < 4; ++t) acc[t] = bias;

        #pragma unroll
        for (int kb = 0; kb < 4; ++kb) {
            #pragma unroll
            for (int c = 0; c < 4; ++c) {
                float h[8];
                #pragma unroll
                for (int u = 0; u < 8; ++u) {
                    const float4 cf = coef4[kb*32 + c*8 + u];
                    h[u] = fmaxf(fmaf(cf.x, px, fmaf(cf.y, py, fmaf(cf.z, sc, cf.w))), 0.f);
                }
                int4 hd = make_int4(cvt_pk_bf16(h[0], h[1]), cvt_pk_bf16(h[2], h[3]),
                                    cvt_pk_bf16(h[4], h[5]), cvt_pk_bf16(h[6], h[7]));
                *(int4*)(hw + lane*32 + ((c ^ wswz) << 3)) = hd;
            }
            __builtin_amdgcn_wave_barrier();
            bf16x8 af = *(const bf16x8*)(w2lds + (kb*64 + lane)*8);
            #pragma unroll
            for (int t = 0; t < 4; ++t) {
                const int pp = t*16 + q;
                bf16x8 bfrag = *(const bf16x8*)(hw + pp*32 + (((g ^ rsw) & 3) << 3));
                acc[t] = __builtin_amdgcn_mfma_f32_16x16x32_bf16(
                             af, bfrag, acc[t], 0, 0, 0);
            }
            __builtin_amdgcn_wave_barrier();
        }

        // ---- epilogue: direct stores, lane holds dx[ch=g*4+r][px=t*16+q] ----
        #pragma unroll
        for (int t = 0; t < 4; ++t) {
            const int pp = pstrip + t*16 + q;
            float xn3 = 0.f;
            #pragma unroll
            for (int e = 0; e < 4; ++e) {
                const int ch = g*4 + e;
                float xv = xb[ch*HW_ + pp];     // just-summed row -> L2/L3 hit
                float xn = fmaf(acc[t][e], mv[t], xv);
                ob[ch*HW_ + pp] = xn;
                if (ch == 3) xn3 = xn;
            }
            if (g == 0) ab[pp] = (xn3 > 0.1f) ? (unsigned char)1
                                              : (unsigned char)0;
        }
    }
}

// ---------------- k3: kill pixels with no alive neighbor ---------------------
__global__ __launch_bounds__(256) void nca_alive(
    const unsigned char* __restrict__ alpha, float* __restrict__ out)
{
    int t = blockIdx.x * blockDim.x + threadIdx.x;
    if (t >= B_*HW_) return;
    int b = t >> 16;
    int p = t & (HW_-1);
    int i = p >> 8;
    int j = p & (W_-1);
    const unsigned char* ab = alpha + (size_t)b * HW_;

    bool im = i > 0, ip = i < H_-1, jm = j > 0, jp = j < W_-1;
    int acc = ab[p];
    acc += jm ? ab[p-1] : 0;
    acc += jp ? ab[p+1] : 0;
    if (im) {
        acc += ab[p-W_];
        acc += jm ? ab[p-W_-1] : 0;
        acc += jp ? ab[p-W_+1] : 0;
    }
    if (ip) {
        acc += ab[p+W_];
        acc += jm ? ab[p+W_-1] : 0;
        acc += jp ? ab[p+W_+1] : 0;
    }
    if (acc == 0) {
        size_t base = (size_t)b * C_ * HW_ + p;
        #pragma unroll
        for (int c = 0; c < C_; ++c) out[base + (size_t)c * HW_] = 0.f;
    }
}

extern "C" void kernel_launch(void* const* d_in, const int* in_sizes, int n_in,
                              void* d_out, int out_size, void* d_ws, size_t ws_size,
                              hipStream_t stream)
{
    const float* x    = (const float*)d_in[0];
    const int*   mask = (const int*)d_in[1];
    const float* w1   = (const float*)d_in[2];
    const float* b1   = (const float*)d_in[3];
    const float* w2   = (const float*)d_in[4];
    const float* b2   = (const float*)d_in[5];
    float* out = (float*)d_out;

    // ws layout: alpha (B*HW bytes) | coef4 (128 float4)
    char* ws = (char*)d_ws;
    unsigned char* alpha = (unsigned char*)ws;
    float4*        coef4 = (float4*)(ws + (size_t)B_*HW_);

    nca_prep<<<1, 128, 0, stream>>>(w1, b1, coef4);

    nca_fused<<<NBLK_, 256, 0, stream>>>(x, mask, coef4, w2, b2, out, alpha);

    int n = B_*HW_;
    nca_alive<<<(n + 255)/256, 256, 0, stream>>>(alpha, out);
}